// Round 6
// baseline (6324.931 us; speedup 1.0000x reference)
//
#include <hip/hip_runtime.h>
#include <hip/hip_bf16.h>

// Problem constants
#define B_    32
#define S_    512
#define E_    512
#define H_    1024          // U_DIM
#define G4_   4096          // 4*U_DIM
#define NB_   64            // scan blocks
#define HPAD_ 1048          // Hs row stride bytes (1024 + 24; dword stride 262 -> 6*lr bank spread)

typedef __attribute__((ext_vector_type(8))) short short8;
typedef __attribute__((ext_vector_type(4))) float f32x4;
typedef unsigned long long u64;

__device__ __forceinline__ float bf2f(ushort u) {
    union { unsigned u32; float f; } cv; cv.u32 = ((unsigned)u) << 16; return cv.f;
}
__device__ __forceinline__ ushort f2bf(float f) {
    union { float f; unsigned u; } cv; cv.f = f;
    unsigned u = cv.u;
    u += 0x7FFFu + ((u >> 16) & 1u);   // RNE
    return (ushort)(u >> 16);
}
__device__ __forceinline__ float tanh_fast(float x) {
    float e = __builtin_amdgcn_exp2f(x * 2.885390081777927f);
    return 1.0f - 2.0f * __builtin_amdgcn_rcpf(e + 1.0f);
}
__device__ __forceinline__ float sel4(int s, float a0, float a1, float a2, float a3) {
    return (s & 2) ? ((s & 1) ? a3 : a2) : ((s & 1) ? a1 : a0);
}

// ---------------- init: zero h0 (tagged: data=0, tag=0), build per-step row masks ----------------
__global__ void init_kernel(const int* __restrict__ tokens, u64* hA, unsigned* __restrict__ m32) {
    int i = blockIdx.x * 256 + threadIdx.x;   // grid 16x256 -> 0..4095
    hA[i] = 0ull; hA[i + 4096] = 0ull;        // 8192 tagged chunks (64 KB)
    if (i < 512) {
        unsigned m = 0;
        for (int b = 0; b < 32; ++b)
            m |= (tokens[b * S_ + i] != 0 ? 1u : 0u) << b;
        m32[i] = m;
    }
}

// ---------------- W transpose: fp32 [E][G4] -> bf16 WT[n][k] ----------------
__global__ void transpose_w_kernel(const float* __restrict__ src, ushort* __restrict__ dst) {
    __shared__ float tile[32][33];
    int kx = blockIdx.y * 32;
    int nx = blockIdx.x * 32;
    int c  = threadIdx.x & 31;
    int r0 = threadIdx.x >> 5;
    for (int rr = r0; rr < 32; rr += 8)
        tile[rr][c] = src[(size_t)(kx + rr) * G4_ + nx + c];
    __syncthreads();
    for (int rr = r0; rr < 32; rr += 8)
        dst[(size_t)(nx + rr) * E_ + kx + c] = f2bf(tile[c][rr]);
}

// ---------------- U transpose: fp32 [H][G4] -> fp8(e4m3, x64) UT[n'][k], n'=j*4+g ----------------
__global__ void transpose_u_kernel(const float* __restrict__ src, unsigned* __restrict__ dst) {
    __shared__ float tile[32][33];
    int kx = blockIdx.y * 32;
    int nx = blockIdx.x * 32;
    int c  = threadIdx.x & 31;
    int r0 = threadIdx.x >> 5;
    for (int rr = r0; rr < 32; rr += 8)
        tile[rr][c] = src[(size_t)(kx + rr) * G4_ + nx + c];
    __syncthreads();
    int r  = threadIdx.x >> 3;    // n-index in tile 0..31
    int c3 = threadIdx.x & 7;     // k-quad
    int n  = nx + r;
    int np = (n & 1023) * 4 + (n >> 10);
    float v0 = tile[c3 * 4 + 0][r] * 64.0f;
    float v1 = tile[c3 * 4 + 1][r] * 64.0f;
    float v2 = tile[c3 * 4 + 2][r] * 64.0f;
    float v3 = tile[c3 * 4 + 3][r] * 64.0f;
    int pk = __builtin_amdgcn_cvt_pk_fp8_f32(v0, v1, 0, false);
    pk     = __builtin_amdgcn_cvt_pk_fp8_f32(v2, v3, pk, true);
    dst[((size_t)np * H_ + kx + c3 * 4) >> 2] = (unsigned)pk;
}

// ---------------- xW GEMM: emb[tok] @ W + b  -> xWT[t][n'][b] bf16 (coalesced via LDS) ----------------
__global__ __launch_bounds__(256, 1) void gemm_xw_kernel(
    const int* __restrict__ tokens, const float* __restrict__ emb,
    const ushort* __restrict__ WT,  const float* __restrict__ bias,
    ushort* __restrict__ xWT) {
    __shared__ u64 Cs[1024];
    const int tid  = threadIdx.x;
    const int lane = tid & 63;
    const int w    = tid >> 6;
    const int jb   = blockIdx.x;      // 0..63  (j-block of 16)
    const int mb   = blockIdx.y;      // 0..255 (t-pair)
    const int lr = lane & 15, lq = lane >> 4;

    const int t    = mb * 2 + (w >> 1);
    const int brow = (w & 1) * 16 + lr;
    const int tok  = tokens[brow * S_ + t];
    const float* arow = emb + (size_t)tok * E_;

    f32x4 acc[4] = {{0,0,0,0},{0,0,0,0},{0,0,0,0},{0,0,0,0}};
    #pragma unroll 4
    for (int ks = 0; ks < E_ / 32; ++ks) {
        const float* ap = arow + ks * 32 + lq * 8;
        float4 a0 = *reinterpret_cast<const float4*>(ap);
        float4 a1 = *reinterpret_cast<const float4*>(ap + 4);
        short8 af;
        af[0] = (short)f2bf(a0.x); af[1] = (short)f2bf(a0.y);
        af[2] = (short)f2bf(a0.z); af[3] = (short)f2bf(a0.w);
        af[4] = (short)f2bf(a1.x); af[5] = (short)f2bf(a1.y);
        af[6] = (short)f2bf(a1.z); af[7] = (short)f2bf(a1.w);
        #pragma unroll
        for (int s = 0; s < 4; ++s) {
            const ushort* brow_p = WT + (size_t)(s * 1024 + jb * 16 + lr) * E_;
            short8 bf = *reinterpret_cast<const short8*>(brow_p + ks * 32 + lq * 8);
            acc[s] = __builtin_amdgcn_mfma_f32_16x16x32_bf16(af, bf, acc[s], 0, 0, 0);
        }
    }
    #pragma unroll
    for (int s = 0; s < 4; ++s) {
        float bv = bias[s * 1024 + jb * 16 + lr];
        u64 pk = 0;
        #pragma unroll
        for (int r = 0; r < 4; ++r)
            pk |= (u64)f2bf(acc[s][r] + bv) << (16 * r);
        int npl = lr * 4 + s;
        int b4  = (w & 1) * 4 + lq;
        Cs[((w >> 1) * 64 + npl) * 8 + b4] = pk;
    }
    __syncthreads();
    #pragma unroll
    for (int i = 0; i < 4; ++i) {
        int e   = tid + i * 256;
        int tp  = e >> 9;
        int rem = e & 511;
        size_t base = ((size_t)(mb * 2 + tp) * G4_ + jb * 64) * B_;
        *reinterpret_cast<u64*>(xWT + base + rem * 4) = Cs[e];
    }
}

// ---------------- persistent LSTM scan: data-as-flag lockstep ----------------
// 64 blocks x 256 thr. Block = 32 rows x 64 n'-cols. U fragments pinned in regs.
// h exchanged as tagged chunks via LLC: u64 = 4 fp8 (low) | step-tag (high).
// Consumers poll the data itself -> 2 LLC RTs per step instead of ~5.
// One __syncthreads per step (global poll subsumes local read/write ordering).
__global__ __launch_bounds__(256, 1) void scan_kernel(
    const unsigned char* __restrict__ UT,  // fp8 [4096][1024]
    const ushort* __restrict__ xWT,        // bf16 [512][4096][32]
    const unsigned* __restrict__ m32,      // [512] row masks
    u64* hA, u64* hB,                      // tagged h chunks [32][256] ping-pong
    float* __restrict__ out) {             // [3][32][1024] fp32
    __shared__ unsigned char Hs[32 * HPAD_];   // 33.5 KB fp8 h stage

    const int tid  = threadIdx.x;
    const int blk  = blockIdx.x;
    const int lane = tid & 63;
    const int w    = tid >> 6;            // 0..3
    const int lr = lane & 15, lq = lane >> 4;
    const int m0 = (w & 1) * 16;          // row group
    const int n0 = blk * 64 + (w >> 1) * 32;
    const int c0 = n0 + lr;               // tile0 global n'
    const int c1 = n0 + 16 + lr;          // tile1 global n'
    const int g  = lr & 3;                // gate id
    const int cb = blk * 4 + (w >> 1) * 2;  // chunk base (units of 4 j)

    // step-invariant B fragments -> pinned regs (VGPR/AGPR)
    u64 ub0[32], ub1[32];
    #pragma unroll
    for (int ks = 0; ks < 32; ++ks) {
        ub0[ks] = *reinterpret_cast<const u64*>(UT + (size_t)c0 * H_ + ks * 32 + lq * 8);
        ub1[ks] = *reinterpret_cast<const u64*>(UT + (size_t)c1 * H_ + ks * 32 + lq * 8);
    }
    #pragma unroll
    for (int ks = 0; ks < 32; ++ks) {
        asm volatile("" : "+v"(ub0[ks]));
        asm volatile("" : "+v"(ub1[ks]));
    }

    float creg0[4] = {0,0,0,0}, hreg0[4] = {0,0,0,0};
    float creg1[4] = {0,0,0,0}, hreg1[4] = {0,0,0,0};

    const u64* hcur = hA;
    u64*       hnxt = hB;

    // t=0 inputs
    u64 xwv0 = *reinterpret_cast<const u64*>(xWT + ((size_t)0 * G4_ + c0) * B_ + m0 + lq * 4);
    u64 xwv1 = *reinterpret_cast<const u64*>(xWT + ((size_t)0 * G4_ + c1) * B_ + m0 + lq * 4);
    unsigned mask = m32[0];

    for (int t = 0; t < S_; ++t) {
        // ---- poll+stage: 32 tagged chunks/thread; thread tid handles row i, col-chunk tid ----
        {
            const unsigned tv = (unsigned)t;
            u64 hv[32];
            #pragma unroll
            for (int i = 0; i < 32; ++i)
                hv[i] = __hip_atomic_load(hcur + tid + i * 256,
                                          __ATOMIC_RELAXED, __HIP_MEMORY_SCOPE_AGENT);
            unsigned pend = 0u;
            #pragma unroll
            for (int i = 0; i < 32; ++i)
                pend |= ((unsigned)(hv[i] >> 32) != tv) ? (1u << i) : 0u;
            while (__any(pend != 0u)) {
                __builtin_amdgcn_s_sleep(2);
                #pragma unroll
                for (int i = 0; i < 32; ++i) {
                    if (pend & (1u << i)) {
                        u64 v = __hip_atomic_load(hcur + tid + i * 256,
                                                  __ATOMIC_RELAXED, __HIP_MEMORY_SCOPE_AGENT);
                        if ((unsigned)(v >> 32) == tv) { hv[i] = v; pend &= ~(1u << i); }
                    }
                }
            }
            #pragma unroll
            for (int i = 0; i < 32; ++i)
                *reinterpret_cast<unsigned*>(&Hs[i * HPAD_ + tid * 4]) = (unsigned)hv[i];
        }
        __syncthreads();

        // ---- z-tiles = h @ U (fp8 MFMA, K=1024, shared A-frag) ----
        f32x4 acc0 = {0,0,0,0}, acc1 = {0,0,0,0};
        #pragma unroll
        for (int ks = 0; ks < 32; ++ks) {
            u64 af = *reinterpret_cast<const u64*>(&Hs[(m0 + lr) * HPAD_ + ks * 32 + lq * 8]);
            acc0 = __builtin_amdgcn_mfma_f32_16x16x32_fp8_fp8((long)af, (long)ub0[ks], acc0, 0, 0, 0);
            acc1 = __builtin_amdgcn_mfma_f32_16x16x32_fp8_fp8((long)af, (long)ub1[ks], acc1, 0, 0, 0);
        }

        // ---- gates ----
        #pragma unroll
        for (int r = 0; r < 4; ++r) {
            bool mb = (mask >> (m0 + lq * 4 + r)) & 1;
            {
                float z  = acc0[r] * (1.0f / 16384.0f) + bf2f((ushort)(xwv0 >> (16 * r)));
                float tg = tanh_fast(z);
                float x1 = __shfl_xor(tg, 1, 64);
                float x2 = __shfl_xor(tg, 2, 64);
                float x3 = __shfl_xor(tg, 3, 64);
                float tI = sel4(g,     tg, x1, x2, x3);
                float tF = sel4(g ^ 1, tg, x1, x2, x3);
                float tG = sel4(g ^ 2, tg, x1, x2, x3);
                float tO = sel4(g ^ 3, tg, x1, x2, x3);
                float cn = tF * creg0[r] + tI * tG;
                float hn = tO * tanh_fast(cn);
                if (mb) { creg0[r] = cn; hreg0[r] = hn; }
            }
            {
                float z  = acc1[r] * (1.0f / 16384.0f) + bf2f((ushort)(xwv1 >> (16 * r)));
                float tg = tanh_fast(z);
                float x1 = __shfl_xor(tg, 1, 64);
                float x2 = __shfl_xor(tg, 2, 64);
                float x3 = __shfl_xor(tg, 3, 64);
                float tI = sel4(g,     tg, x1, x2, x3);
                float tF = sel4(g ^ 1, tg, x1, x2, x3);
                float tG = sel4(g ^ 2, tg, x1, x2, x3);
                float tO = sel4(g ^ 3, tg, x1, x2, x3);
                float cn = tF * creg1[r] + tI * tG;
                float hn = tO * tanh_fast(cn);
                if (mb) { creg1[r] = cn; hreg1[r] = hn; }
            }
        }

        if (t < S_ - 1) {
            // ---- pack per tile: 4 fp8 (x256) + tag -> tagged u64 stores on lr==0 lanes ----
            const u64 tagw = (u64)(unsigned)(t + 1) << 32;
            #pragma unroll
            for (int r = 0; r < 4; ++r) {
                float a0 = hreg0[r] * 256.0f;
                float b0 = __shfl_xor(a0, 4, 64);
                float cc0 = __shfl_xor(a0, 8, 64);
                float d0 = __shfl_xor(a0, 12, 64);
                int pk0 = __builtin_amdgcn_cvt_pk_fp8_f32(a0, b0, 0, false);
                pk0     = __builtin_amdgcn_cvt_pk_fp8_f32(cc0, d0, pk0, true);
                float a1 = hreg1[r] * 256.0f;
                float b1 = __shfl_xor(a1, 4, 64);
                float cc1 = __shfl_xor(a1, 8, 64);
                float d1 = __shfl_xor(a1, 12, 64);
                int pk1 = __builtin_amdgcn_cvt_pk_fp8_f32(a1, b1, 0, false);
                pk1     = __builtin_amdgcn_cvt_pk_fp8_f32(cc1, d1, pk1, true);
                if (lr == 0) {
                    int row = m0 + lq * 4 + r;
                    __hip_atomic_store(hnxt + row * 256 + cb,     (u64)(unsigned)pk0 | tagw,
                                       __ATOMIC_RELAXED, __HIP_MEMORY_SCOPE_AGENT);
                    __hip_atomic_store(hnxt + row * 256 + cb + 1, (u64)(unsigned)pk1 | tagw,
                                       __ATOMIC_RELAXED, __HIP_MEMORY_SCOPE_AGENT);
                }
            }
            // prefetch next-step inputs (overlaps with other blocks' polling)
            xwv0 = *reinterpret_cast<const u64*>(xWT + ((size_t)(t + 1) * G4_ + c0) * B_ + m0 + lq * 4);
            xwv1 = *reinterpret_cast<const u64*>(xWT + ((size_t)(t + 1) * G4_ + c1) * B_ + m0 + lq * 4);
            mask = m32[t + 1];
            const u64* tsw = hcur; hcur = hnxt; hnxt = (u64*)tsw;
        } else {
            // ---- final: write (h, h, c) fp32 ----
            if (g == 0) {
                int j0 = c0 >> 2, j1 = c1 >> 2;
                #pragma unroll
                for (int r = 0; r < 4; ++r) {
                    int row = m0 + lq * 4 + r;
                    out[row * H_ + j0]               = hreg0[r];
                    out[B_ * H_ + row * H_ + j0]     = hreg0[r];
                    out[2 * B_ * H_ + row * H_ + j0] = creg0[r];
                    out[row * H_ + j1]               = hreg1[r];
                    out[B_ * H_ + row * H_ + j1]     = hreg1[r];
                    out[2 * B_ * H_ + row * H_ + j1] = creg1[r];
                }
            }
        }
    }
}

extern "C" void kernel_launch(void* const* d_in, const int* in_sizes, int n_in,
                              void* d_out, int out_size, void* d_ws, size_t ws_size,
                              hipStream_t stream) {
    (void)in_sizes; (void)n_in; (void)out_size; (void)ws_size;
    const int*   tokens = (const int*)  d_in[0];
    const float* emb    = (const float*)d_in[1];
    const float* W      = (const float*)d_in[2];
    const float* U      = (const float*)d_in[3];
    const float* bias   = (const float*)d_in[4];

    char* ws = (char*)d_ws;
    ushort*        WT   = (ushort*)ws;                               // 4 MB
    unsigned char* UT   = (unsigned char*)(ws + (4u << 20));         // 4 MB fp8
    ushort*        xWT  = (ushort*)(ws + (8u << 20));                // 128 MB
    u64*           hA   = (u64*)(ws + (136u << 20));                 // 64 KB tagged
    u64*           hB   = hA + 8192;                                 // 64 KB tagged
    unsigned*      m32  = (unsigned*)(hB + 8192);                    // 2 KB

    init_kernel<<<16, 256, 0, stream>>>(tokens, hA, m32);
    transpose_w_kernel<<<dim3(G4_ / 32, E_ / 32), 256, 0, stream>>>(W, WT);
    transpose_u_kernel<<<dim3(G4_ / 32, H_ / 32), 256, 0, stream>>>(U, (unsigned*)UT);
    gemm_xw_kernel<<<dim3(64, 256), 256, 0, stream>>>(tokens, emb, WT, bias, xWT);
    scan_kernel<<<NB_, 256, 0, stream>>>(UT, xWT, m32, hA, hB, (float*)d_out);
}

// Round 7
// 2780.901 us; speedup vs baseline: 2.2744x; 2.2744x over previous
//
#include <hip/hip_runtime.h>
#include <hip/hip_bf16.h>

// Problem constants
#define B_    32
#define S_    512
#define E_    512
#define H_    1024          // U_DIM
#define G4_   4096          // 4*U_DIM
#define NB_   64            // scan blocks
#define HPAD_ 1048          // Hs row stride bytes

typedef __attribute__((ext_vector_type(8))) short short8;
typedef __attribute__((ext_vector_type(4))) float f32x4;
typedef unsigned long long u64;

__device__ __forceinline__ float bf2f(ushort u) {
    union { unsigned u32; float f; } cv; cv.u32 = ((unsigned)u) << 16; return cv.f;
}
__device__ __forceinline__ ushort f2bf(float f) {
    union { float f; unsigned u; } cv; cv.f = f;
    unsigned u = cv.u;
    u += 0x7FFFu + ((u >> 16) & 1u);   // RNE
    return (ushort)(u >> 16);
}
__device__ __forceinline__ float tanh_fast(float x) {
    float e = __builtin_amdgcn_exp2f(x * 2.885390081777927f);
    return 1.0f - 2.0f * __builtin_amdgcn_rcpf(e + 1.0f);
}
__device__ __forceinline__ float sel4(int s, float a0, float a1, float a2, float a3) {
    return (s & 2) ? ((s & 1) ? a3 : a2) : ((s & 1) ? a1 : a0);
}

// ---------------- init: zero h0 (tagged: data=0, tag=0), build per-step row masks ----------------
__global__ void init_kernel(const int* __restrict__ tokens, u64* hA, unsigned* __restrict__ m32) {
    int i = blockIdx.x * 256 + threadIdx.x;   // grid 16x256 -> 0..4095
    hA[i] = 0ull; hA[i + 4096] = 0ull;        // 8192 tagged chunks (64 KB)
    if (i < 512) {
        unsigned m = 0;
        for (int b = 0; b < 32; ++b)
            m |= (tokens[b * S_ + i] != 0 ? 1u : 0u) << b;
        m32[i] = m;
    }
}

// ---------------- W transpose: fp32 [E][G4] -> bf16 WT[n][k] ----------------
__global__ void transpose_w_kernel(const float* __restrict__ src, ushort* __restrict__ dst) {
    __shared__ float tile[32][33];
    int kx = blockIdx.y * 32;
    int nx = blockIdx.x * 32;
    int c  = threadIdx.x & 31;
    int r0 = threadIdx.x >> 5;
    for (int rr = r0; rr < 32; rr += 8)
        tile[rr][c] = src[(size_t)(kx + rr) * G4_ + nx + c];
    __syncthreads();
    for (int rr = r0; rr < 32; rr += 8)
        dst[(size_t)(nx + rr) * E_ + kx + c] = f2bf(tile[c][rr]);
}

// ---------------- U transpose: fp32 [H][G4] -> fp8(e4m3, x64) UT[n'][k], n'=j*4+g ----------------
__global__ void transpose_u_kernel(const float* __restrict__ src, unsigned* __restrict__ dst) {
    __shared__ float tile[32][33];
    int kx = blockIdx.y * 32;
    int nx = blockIdx.x * 32;
    int c  = threadIdx.x & 31;
    int r0 = threadIdx.x >> 5;
    for (int rr = r0; rr < 32; rr += 8)
        tile[rr][c] = src[(size_t)(kx + rr) * G4_ + nx + c];
    __syncthreads();
    int r  = threadIdx.x >> 3;    // n-index in tile 0..31
    int c3 = threadIdx.x & 7;     // k-quad
    int n  = nx + r;
    int np = (n & 1023) * 4 + (n >> 10);
    float v0 = tile[c3 * 4 + 0][r] * 64.0f;
    float v1 = tile[c3 * 4 + 1][r] * 64.0f;
    float v2 = tile[c3 * 4 + 2][r] * 64.0f;
    float v3 = tile[c3 * 4 + 3][r] * 64.0f;
    int pk = __builtin_amdgcn_cvt_pk_fp8_f32(v0, v1, 0, false);
    pk     = __builtin_amdgcn_cvt_pk_fp8_f32(v2, v3, pk, true);
    dst[((size_t)np * H_ + kx + c3 * 4) >> 2] = (unsigned)pk;
}

// ---------------- xW GEMM: emb[tok] @ W + b  -> xWT[t][n'][b] bf16 (coalesced via LDS) ----------------
__global__ __launch_bounds__(256, 1) void gemm_xw_kernel(
    const int* __restrict__ tokens, const float* __restrict__ emb,
    const ushort* __restrict__ WT,  const float* __restrict__ bias,
    ushort* __restrict__ xWT) {
    __shared__ u64 Cs[1024];
    const int tid  = threadIdx.x;
    const int lane = tid & 63;
    const int w    = tid >> 6;
    const int jb   = blockIdx.x;      // 0..63  (j-block of 16)
    const int mb   = blockIdx.y;      // 0..255 (t-pair)
    const int lr = lane & 15, lq = lane >> 4;

    const int t    = mb * 2 + (w >> 1);
    const int brow = (w & 1) * 16 + lr;
    const int tok  = tokens[brow * S_ + t];
    const float* arow = emb + (size_t)tok * E_;

    f32x4 acc[4] = {{0,0,0,0},{0,0,0,0},{0,0,0,0},{0,0,0,0}};
    #pragma unroll 4
    for (int ks = 0; ks < E_ / 32; ++ks) {
        const float* ap = arow + ks * 32 + lq * 8;
        float4 a0 = *reinterpret_cast<const float4*>(ap);
        float4 a1 = *reinterpret_cast<const float4*>(ap + 4);
        short8 af;
        af[0] = (short)f2bf(a0.x); af[1] = (short)f2bf(a0.y);
        af[2] = (short)f2bf(a0.z); af[3] = (short)f2bf(a0.w);
        af[4] = (short)f2bf(a1.x); af[5] = (short)f2bf(a1.y);
        af[6] = (short)f2bf(a1.z); af[7] = (short)f2bf(a1.w);
        #pragma unroll
        for (int s = 0; s < 4; ++s) {
            const ushort* brow_p = WT + (size_t)(s * 1024 + jb * 16 + lr) * E_;
            short8 bf = *reinterpret_cast<const short8*>(brow_p + ks * 32 + lq * 8);
            acc[s] = __builtin_amdgcn_mfma_f32_16x16x32_bf16(af, bf, acc[s], 0, 0, 0);
        }
    }
    #pragma unroll
    for (int s = 0; s < 4; ++s) {
        float bv = bias[s * 1024 + jb * 16 + lr];
        u64 pk = 0;
        #pragma unroll
        for (int r = 0; r < 4; ++r)
            pk |= (u64)f2bf(acc[s][r] + bv) << (16 * r);
        int npl = lr * 4 + s;
        int b4  = (w & 1) * 4 + lq;
        Cs[((w >> 1) * 64 + npl) * 8 + b4] = pk;
    }
    __syncthreads();
    #pragma unroll
    for (int i = 0; i < 4; ++i) {
        int e   = tid + i * 256;
        int tp  = e >> 9;
        int rem = e & 511;
        size_t base = ((size_t)(mb * 2 + tp) * G4_ + jb * 64) * B_;
        *reinterpret_cast<u64*>(xWT + base + rem * 4) = Cs[e];
    }
}

// ---------------- persistent LSTM scan: data-as-flag lockstep, pipelined poll ----------------
// 64 blocks x 256 thr. Block = 32 rows x 64 n'-cols. U fragments pinned in regs.
// h exchanged as tagged chunks via LLC: u64 = 4 fp8 (low) | step-tag (high).
// Poll = unconditional 32-load pipelined burst per round (NO divergent per-chunk
// retries -- that serialized 32 LLC RTs in R6). Values stable once fresh.
__global__ __launch_bounds__(256, 1) void scan_kernel(
    const unsigned char* __restrict__ UT,  // fp8 [4096][1024]
    const ushort* __restrict__ xWT,        // bf16 [512][4096][32]
    const unsigned* __restrict__ m32,      // [512] row masks
    u64* hA, u64* hB,                      // tagged h chunks [32][256] ping-pong
    float* __restrict__ out) {             // [3][32][1024] fp32
    __shared__ unsigned char Hs[32 * HPAD_];   // 33.5 KB fp8 h stage

    const int tid  = threadIdx.x;
    const int blk  = blockIdx.x;
    const int lane = tid & 63;
    const int w    = tid >> 6;            // 0..3
    const int lr = lane & 15, lq = lane >> 4;
    const int m0 = (w & 1) * 16;          // row group
    const int n0 = blk * 64 + (w >> 1) * 32;
    const int c0 = n0 + lr;               // tile0 global n'
    const int c1 = n0 + 16 + lr;          // tile1 global n'
    const int g  = lr & 3;                // gate id
    const int cb = blk * 4 + (w >> 1) * 2;  // chunk base (units of 4 j)

    // step-invariant B fragments -> pinned regs (VGPR/AGPR)
    u64 ub0[32], ub1[32];
    #pragma unroll
    for (int ks = 0; ks < 32; ++ks) {
        ub0[ks] = *reinterpret_cast<const u64*>(UT + (size_t)c0 * H_ + ks * 32 + lq * 8);
        ub1[ks] = *reinterpret_cast<const u64*>(UT + (size_t)c1 * H_ + ks * 32 + lq * 8);
    }
    #pragma unroll
    for (int ks = 0; ks < 32; ++ks) {
        asm volatile("" : "+v"(ub0[ks]));
        asm volatile("" : "+v"(ub1[ks]));
    }

    float creg0[4] = {0,0,0,0}, hreg0[4] = {0,0,0,0};
    float creg1[4] = {0,0,0,0}, hreg1[4] = {0,0,0,0};

    const u64* hcur = hA;
    u64*       hnxt = hB;

    // t=0 inputs
    u64 xwv0 = *reinterpret_cast<const u64*>(xWT + ((size_t)0 * G4_ + c0) * B_ + m0 + lq * 4);
    u64 xwv1 = *reinterpret_cast<const u64*>(xWT + ((size_t)0 * G4_ + c1) * B_ + m0 + lq * 4);
    unsigned mask = m32[0];

    for (int t = 0; t < S_; ++t) {
        // ---- poll+stage: unconditional pipelined 32-load bursts until all tags fresh ----
        {
            const unsigned tv = (unsigned)t;
            u64 hv[32];
            for (;;) {
                #pragma unroll
                for (int i = 0; i < 32; ++i)
                    hv[i] = __hip_atomic_load(hcur + tid + i * 256,
                                              __ATOMIC_RELAXED, __HIP_MEMORY_SCOPE_AGENT);
                unsigned bad = 0u;
                #pragma unroll
                for (int i = 0; i < 32; ++i)
                    bad |= ((unsigned)(hv[i] >> 32)) ^ tv;
                if (__all(bad == 0u)) break;
                __builtin_amdgcn_s_sleep(1);
            }
            #pragma unroll
            for (int i = 0; i < 32; ++i)
                *reinterpret_cast<unsigned*>(&Hs[i * HPAD_ + tid * 4]) = (unsigned)hv[i];
        }
        __syncthreads();

        // ---- z-tiles = h @ U (fp8 MFMA, K=1024, shared A-frag) ----
        f32x4 acc0 = {0,0,0,0}, acc1 = {0,0,0,0};
        #pragma unroll
        for (int ks = 0; ks < 32; ++ks) {
            u64 af = *reinterpret_cast<const u64*>(&Hs[(m0 + lr) * HPAD_ + ks * 32 + lq * 8]);
            acc0 = __builtin_amdgcn_mfma_f32_16x16x32_fp8_fp8((long)af, (long)ub0[ks], acc0, 0, 0, 0);
            acc1 = __builtin_amdgcn_mfma_f32_16x16x32_fp8_fp8((long)af, (long)ub1[ks], acc1, 0, 0, 0);
        }

        // ---- gates ----
        #pragma unroll
        for (int r = 0; r < 4; ++r) {
            bool mb = (mask >> (m0 + lq * 4 + r)) & 1;
            {
                float z  = acc0[r] * (1.0f / 16384.0f) + bf2f((ushort)(xwv0 >> (16 * r)));
                float tg = tanh_fast(z);
                float x1 = __shfl_xor(tg, 1, 64);
                float x2 = __shfl_xor(tg, 2, 64);
                float x3 = __shfl_xor(tg, 3, 64);
                float tI = sel4(g,     tg, x1, x2, x3);
                float tF = sel4(g ^ 1, tg, x1, x2, x3);
                float tG = sel4(g ^ 2, tg, x1, x2, x3);
                float tO = sel4(g ^ 3, tg, x1, x2, x3);
                float cn = tF * creg0[r] + tI * tG;
                float hn = tO * tanh_fast(cn);
                if (mb) { creg0[r] = cn; hreg0[r] = hn; }
            }
            {
                float z  = acc1[r] * (1.0f / 16384.0f) + bf2f((ushort)(xwv1 >> (16 * r)));
                float tg = tanh_fast(z);
                float x1 = __shfl_xor(tg, 1, 64);
                float x2 = __shfl_xor(tg, 2, 64);
                float x3 = __shfl_xor(tg, 3, 64);
                float tI = sel4(g,     tg, x1, x2, x3);
                float tF = sel4(g ^ 1, tg, x1, x2, x3);
                float tG = sel4(g ^ 2, tg, x1, x2, x3);
                float tO = sel4(g ^ 3, tg, x1, x2, x3);
                float cn = tF * creg1[r] + tI * tG;
                float hn = tO * tanh_fast(cn);
                if (mb) { creg1[r] = cn; hreg1[r] = hn; }
            }
        }

        if (t < S_ - 1) {
            // ---- pack per tile: 4 fp8 (x256) + tag -> tagged u64 stores on lr==0 lanes ----
            const u64 tagw = (u64)(unsigned)(t + 1) << 32;
            #pragma unroll
            for (int r = 0; r < 4; ++r) {
                float a0 = hreg0[r] * 256.0f;
                float b0 = __shfl_xor(a0, 4, 64);
                float cc0 = __shfl_xor(a0, 8, 64);
                float d0 = __shfl_xor(a0, 12, 64);
                int pk0 = __builtin_amdgcn_cvt_pk_fp8_f32(a0, b0, 0, false);
                pk0     = __builtin_amdgcn_cvt_pk_fp8_f32(cc0, d0, pk0, true);
                float a1 = hreg1[r] * 256.0f;
                float b1 = __shfl_xor(a1, 4, 64);
                float cc1 = __shfl_xor(a1, 8, 64);
                float d1 = __shfl_xor(a1, 12, 64);
                int pk1 = __builtin_amdgcn_cvt_pk_fp8_f32(a1, b1, 0, false);
                pk1     = __builtin_amdgcn_cvt_pk_fp8_f32(cc1, d1, pk1, true);
                if (lr == 0) {
                    int row = m0 + lq * 4 + r;
                    __hip_atomic_store(hnxt + row * 256 + cb,     (u64)(unsigned)pk0 | tagw,
                                       __ATOMIC_RELAXED, __HIP_MEMORY_SCOPE_AGENT);
                    __hip_atomic_store(hnxt + row * 256 + cb + 1, (u64)(unsigned)pk1 | tagw,
                                       __ATOMIC_RELAXED, __HIP_MEMORY_SCOPE_AGENT);
                }
            }
            // prefetch next-step inputs (overlaps with other blocks' polling)
            xwv0 = *reinterpret_cast<const u64*>(xWT + ((size_t)(t + 1) * G4_ + c0) * B_ + m0 + lq * 4);
            xwv1 = *reinterpret_cast<const u64*>(xWT + ((size_t)(t + 1) * G4_ + c1) * B_ + m0 + lq * 4);
            mask = m32[t + 1];
            const u64* tsw = hcur; hcur = hnxt; hnxt = (u64*)tsw;
        } else {
            // ---- final: write (h, h, c) fp32 ----
            if (g == 0) {
                int j0 = c0 >> 2, j1 = c1 >> 2;
                #pragma unroll
                for (int r = 0; r < 4; ++r) {
                    int row = m0 + lq * 4 + r;
                    out[row * H_ + j0]               = hreg0[r];
                    out[B_ * H_ + row * H_ + j0]     = hreg0[r];
                    out[2 * B_ * H_ + row * H_ + j0] = creg0[r];
                    out[row * H_ + j1]               = hreg1[r];
                    out[B_ * H_ + row * H_ + j1]     = hreg1[r];
                    out[2 * B_ * H_ + row * H_ + j1] = creg1[r];
                }
            }
        }
    }
}

extern "C" void kernel_launch(void* const* d_in, const int* in_sizes, int n_in,
                              void* d_out, int out_size, void* d_ws, size_t ws_size,
                              hipStream_t stream) {
    (void)in_sizes; (void)n_in; (void)out_size; (void)ws_size;
    const int*   tokens = (const int*)  d_in[0];
    const float* emb    = (const float*)d_in[1];
    const float* W      = (const float*)d_in[2];
    const float* U      = (const float*)d_in[3];
    const float* bias   = (const float*)d_in[4];

    char* ws = (char*)d_ws;
    ushort*        WT   = (ushort*)ws;                               // 4 MB
    unsigned char* UT   = (unsigned char*)(ws + (4u << 20));         // 4 MB fp8
    ushort*        xWT  = (ushort*)(ws + (8u << 20));                // 128 MB
    u64*           hA   = (u64*)(ws + (136u << 20));                 // 64 KB tagged
    u64*           hB   = hA + 8192;                                 // 64 KB tagged
    unsigned*      m32  = (unsigned*)(hB + 8192);                    // 2 KB

    init_kernel<<<16, 256, 0, stream>>>(tokens, hA, m32);
    transpose_w_kernel<<<dim3(G4_ / 32, E_ / 32), 256, 0, stream>>>(W, WT);
    transpose_u_kernel<<<dim3(G4_ / 32, H_ / 32), 256, 0, stream>>>(U, (unsigned*)UT);
    gemm_xw_kernel<<<dim3(64, 256), 256, 0, stream>>>(tokens, emb, WT, bias, xWT);
    scan_kernel<<<NB_, 256, 0, stream>>>(UT, xWT, m32, hA, hB, (float*)d_out);
}

// Round 8
// 2183.142 us; speedup vs baseline: 2.8972x; 1.2738x over previous
//
#include <hip/hip_runtime.h>
#include <hip/hip_bf16.h>

// Problem constants
#define B_    32
#define S_    512
#define E_    512
#define H_    1024          // U_DIM
#define G4_   4096          // 4*U_DIM
#define NSB_  64            // scan blocks
#define NGB_  192           // gemm worker blocks
#define HPAD_ 1048          // Hs row stride bytes

typedef __attribute__((ext_vector_type(8))) short short8;
typedef __attribute__((ext_vector_type(4))) float f32x4;
typedef unsigned long long u64;

__device__ __forceinline__ float bf2f(ushort u) {
    union { unsigned u32; float f; } cv; cv.u32 = ((unsigned)u) << 16; return cv.f;
}
__device__ __forceinline__ ushort f2bf(float f) {
    union { float f; unsigned u; } cv; cv.f = f;
    unsigned u = cv.u;
    u += 0x7FFFu + ((u >> 16) & 1u);   // RNE
    return (ushort)(u >> 16);
}
__device__ __forceinline__ float tanh_fast(float x) {
    float e = __builtin_amdgcn_exp2f(x * 2.885390081777927f);
    return 1.0f - 2.0f * __builtin_amdgcn_rcpf(e + 1.0f);
}
__device__ __forceinline__ float sel4(int s, float a0, float a1, float a2, float a3) {
    return (s & 2) ? ((s & 1) ? a3 : a2) : ((s & 1) ? a1 : a0);
}

// ---------------- init: zero h0 tags, cnt, build per-step row masks ----------------
__global__ void init_kernel(const int* __restrict__ tokens, u64* hA, unsigned* cnt,
                            unsigned* __restrict__ m32) {
    int i = blockIdx.x * 256 + threadIdx.x;   // grid 16x256 -> 0..4095
    hA[i] = 0ull; hA[i + 4096] = 0ull;        // hA fully zeroed (tag 0); hB overwritten at t=0
    if (i < 256) cnt[i] = 0u;
    if (i < 512) {
        unsigned m = 0;
        for (int b = 0; b < 32; ++b)
            m |= (tokens[b * S_ + i] != 0 ? 1u : 0u) << b;
        m32[i] = m;
    }
}

// ---------------- W transpose: fp32 [E][G4] -> bf16 WT[n][k] ----------------
__global__ void transpose_w_kernel(const float* __restrict__ src, ushort* __restrict__ dst) {
    __shared__ float tile[32][33];
    int kx = blockIdx.y * 32;
    int nx = blockIdx.x * 32;
    int c  = threadIdx.x & 31;
    int r0 = threadIdx.x >> 5;
    for (int rr = r0; rr < 32; rr += 8)
        tile[rr][c] = src[(size_t)(kx + rr) * G4_ + nx + c];
    __syncthreads();
    for (int rr = r0; rr < 32; rr += 8)
        dst[(size_t)(nx + rr) * E_ + kx + c] = f2bf(tile[c][rr]);
}

// ---------------- U transpose: fp32 [H][G4] -> fp8(e4m3, x64) UT[n'][k], n'=j*4+g ----------------
__global__ void transpose_u_kernel(const float* __restrict__ src, unsigned* __restrict__ dst) {
    __shared__ float tile[32][33];
    int kx = blockIdx.y * 32;
    int nx = blockIdx.x * 32;
    int c  = threadIdx.x & 31;
    int r0 = threadIdx.x >> 5;
    for (int rr = r0; rr < 32; rr += 8)
        tile[rr][c] = src[(size_t)(kx + rr) * G4_ + nx + c];
    __syncthreads();
    int r  = threadIdx.x >> 3;    // n-index in tile 0..31
    int c3 = threadIdx.x & 7;     // k-quad
    int n  = nx + r;
    int np = (n & 1023) * 4 + (n >> 10);
    float v0 = tile[c3 * 4 + 0][r] * 64.0f;
    float v1 = tile[c3 * 4 + 1][r] * 64.0f;
    float v2 = tile[c3 * 4 + 2][r] * 64.0f;
    float v3 = tile[c3 * 4 + 3][r] * 64.0f;
    int pk = __builtin_amdgcn_cvt_pk_fp8_f32(v0, v1, 0, false);
    pk     = __builtin_amdgcn_cvt_pk_fp8_f32(v2, v3, pk, true);
    dst[((size_t)np * H_ + kx + c3 * 4) >> 2] = (unsigned)pk;
}

// ---------------- mono kernel: 64 scan blocks + 192 gemm worker blocks ----------------
// GEMM workers: units (mb 0..255 t-pairs x jb 0..31 128-np tiles), ascending mb.
// Write xWT[t][n'][b] via sc1 stores, bump cnt[mb] after vmcnt-drained barrier.
// Scan blocks: R7 data-as-flag lockstep; xwv prefetch gated on cnt (pipelined check).
__global__ __launch_bounds__(256, 1) void mono_kernel(
    const unsigned char* __restrict__ UT,  // fp8 [4096][1024]
    ushort* xWT,                           // bf16 [512][4096][32] (workers write, scan reads)
    const unsigned* __restrict__ m32,      // [512] row masks
    u64* hA, u64* hB,                      // tagged h chunks [32][256] ping-pong
    unsigned* cnt,                         // [256] per-t-pair completion counters
    float* __restrict__ out,               // [3][32][1024] fp32
    const int* __restrict__ tokens,
    const float* __restrict__ emb,
    const ushort* __restrict__ WT,         // bf16 [4096][512]
    const float* __restrict__ bias) {
    __shared__ u64 smem[4192];             // scan: Hs 33.5 KB | gemm: Cs 16 KB

    const int tid  = threadIdx.x;
    const int lane = tid & 63;
    const int w    = tid >> 6;            // 0..3
    const int lr = lane & 15, lq = lane >> 4;

    if (blockIdx.x >= NSB_) {
        // ================= GEMM worker =================
        const int blkg = blockIdx.x - NSB_;
        u64* Cs = smem;                    // [tp2][npl128][b4 8] u64
        for (int u = blkg; u < 8192; u += NGB_) {
            const int mb = u >> 5, jb = u & 31;
            const int t    = mb * 2 + (w >> 1);
            const int brow = (w & 1) * 16 + lr;
            const int tok  = tokens[brow * S_ + t];
            const float* arow = emb + (size_t)tok * E_;

            f32x4 acc[8] = {{0,0,0,0},{0,0,0,0},{0,0,0,0},{0,0,0,0},
                            {0,0,0,0},{0,0,0,0},{0,0,0,0},{0,0,0,0}};
            #pragma unroll 2
            for (int ks = 0; ks < E_ / 32; ++ks) {
                const float* ap = arow + ks * 32 + lq * 8;
                float4 a0 = *reinterpret_cast<const float4*>(ap);
                float4 a1 = *reinterpret_cast<const float4*>(ap + 4);
                short8 af;
                af[0] = (short)f2bf(a0.x); af[1] = (short)f2bf(a0.y);
                af[2] = (short)f2bf(a0.z); af[3] = (short)f2bf(a0.w);
                af[4] = (short)f2bf(a1.x); af[5] = (short)f2bf(a1.y);
                af[6] = (short)f2bf(a1.z); af[7] = (short)f2bf(a1.w);
                #pragma unroll
                for (int s = 0; s < 4; ++s)
                    #pragma unroll
                    for (int h = 0; h < 2; ++h) {
                        const ushort* bp = WT + (size_t)(s * 1024 + jb * 32 + h * 16 + lr) * E_;
                        short8 bf = *reinterpret_cast<const short8*>(bp + ks * 32 + lq * 8);
                        acc[s * 2 + h] = __builtin_amdgcn_mfma_f32_16x16x32_bf16(af, bf, acc[s * 2 + h], 0, 0, 0);
                    }
            }
            #pragma unroll
            for (int s = 0; s < 4; ++s)
                #pragma unroll
                for (int h = 0; h < 2; ++h) {
                    int n = s * 1024 + jb * 32 + h * 16 + lr;
                    float bv = bias[n];
                    u64 pk = 0;
                    #pragma unroll
                    for (int r = 0; r < 4; ++r)
                        pk |= (u64)f2bf(acc[s * 2 + h][r] + bv) << (16 * r);
                    int npl = (h * 16 + lr) * 4 + s;             // 0..127
                    Cs[((size_t)(w >> 1) * 128 + npl) * 8 + (w & 1) * 4 + lq] = pk;
                }
            __syncthreads();
            #pragma unroll
            for (int i = 0; i < 8; ++i) {
                int e   = tid + i * 256;         // 0..2047
                int tp  = e >> 10;
                int rem = e & 1023;
                u64* dst = (u64*)(xWT + ((size_t)(mb * 2 + tp) * G4_ + jb * 128) * B_) + rem;
                __hip_atomic_store(dst, Cs[e], __ATOMIC_RELAXED, __HIP_MEMORY_SCOPE_AGENT);
            }
            __syncthreads();                     // drains all waves' stores (vmcnt 0)
            if (tid == 0)
                __hip_atomic_fetch_add(&cnt[mb], 1u, __ATOMIC_RELAXED, __HIP_MEMORY_SCOPE_AGENT);
        }
        return;
    }

    // ================= persistent LSTM scan (R7 core) =================
    unsigned char* Hs = (unsigned char*)smem;
    const int blk  = blockIdx.x;
    const int m0 = (w & 1) * 16;          // row group
    const int n0 = blk * 64 + (w >> 1) * 32;
    const int c0 = n0 + lr;               // tile0 global n'
    const int c1 = n0 + 16 + lr;          // tile1 global n'
    const int g  = lr & 3;                // gate id
    const int cb = blk * 4 + (w >> 1) * 2;  // chunk base (units of 4 j)

    // step-invariant B fragments -> pinned regs
    u64 ub0[32], ub1[32];
    #pragma unroll
    for (int ks = 0; ks < 32; ++ks) {
        ub0[ks] = *reinterpret_cast<const u64*>(UT + (size_t)c0 * H_ + ks * 32 + lq * 8);
        ub1[ks] = *reinterpret_cast<const u64*>(UT + (size_t)c1 * H_ + ks * 32 + lq * 8);
    }
    #pragma unroll
    for (int ks = 0; ks < 32; ++ks) {
        asm volatile("" : "+v"(ub0[ks]));
        asm volatile("" : "+v"(ub1[ks]));
    }

    float creg0[4] = {0,0,0,0}, hreg0[4] = {0,0,0,0};
    float creg1[4] = {0,0,0,0}, hreg1[4] = {0,0,0,0};

    const u64* hcur = hA;
    u64*       hnxt = hB;

    // wait for xW slice mb=0 (t=0,1), then load t=0 inputs
    while (__hip_atomic_load(&cnt[0], __ATOMIC_RELAXED, __HIP_MEMORY_SCOPE_AGENT) < 32u)
        __builtin_amdgcn_s_sleep(8);
    asm volatile("" ::: "memory");
    u64 xwv0 = *reinterpret_cast<const u64*>(xWT + ((size_t)0 * G4_ + c0) * B_ + m0 + lq * 4);
    u64 xwv1 = *reinterpret_cast<const u64*>(xWT + ((size_t)0 * G4_ + c1) * B_ + m0 + lq * 4);
    unsigned mask = m32[0];
    int mb_conf = 1;                       // cnt[0] confirmed
    unsigned cv = __hip_atomic_load(&cnt[1], __ATOMIC_RELAXED, __HIP_MEMORY_SCOPE_AGENT);

    for (int t = 0; t < S_; ++t) {
        // ---- poll+stage: unconditional pipelined 32-load bursts until all tags fresh ----
        {
            const unsigned tv = (unsigned)t;
            u64 hv[32];
            for (;;) {
                #pragma unroll
                for (int i = 0; i < 32; ++i)
                    hv[i] = __hip_atomic_load(hcur + tid + i * 256,
                                              __ATOMIC_RELAXED, __HIP_MEMORY_SCOPE_AGENT);
                unsigned bad = 0u;
                #pragma unroll
                for (int i = 0; i < 32; ++i)
                    bad |= ((unsigned)(hv[i] >> 32)) ^ tv;
                if (__all(bad == 0u)) break;
                __builtin_amdgcn_s_sleep(1);
            }
            #pragma unroll
            for (int i = 0; i < 32; ++i)
                *reinterpret_cast<unsigned*>(&Hs[i * HPAD_ + tid * 4]) = (unsigned)hv[i];
        }
        __syncthreads();

        // ---- z-tiles = h @ U (fp8 MFMA, K=1024, shared A-frag) ----
        f32x4 acc0 = {0,0,0,0}, acc1 = {0,0,0,0};
        #pragma unroll
        for (int ks = 0; ks < 32; ++ks) {
            u64 af = *reinterpret_cast<const u64*>(&Hs[(m0 + lr) * HPAD_ + ks * 32 + lq * 8]);
            acc0 = __builtin_amdgcn_mfma_f32_16x16x32_fp8_fp8((long)af, (long)ub0[ks], acc0, 0, 0, 0);
            acc1 = __builtin_amdgcn_mfma_f32_16x16x32_fp8_fp8((long)af, (long)ub1[ks], acc1, 0, 0, 0);
        }

        // ---- gates + (merged) pack/store per r: h stores issue earlier ----
        const u64 tagw = (u64)(unsigned)(t + 1) << 32;
        const bool notlast = (t < S_ - 1);
        #pragma unroll
        for (int r = 0; r < 4; ++r) {
            bool mbk = (mask >> (m0 + lq * 4 + r)) & 1;
            {
                float z  = acc0[r] * (1.0f / 16384.0f) + bf2f((ushort)(xwv0 >> (16 * r)));
                float tg = tanh_fast(z);
                float x1 = __shfl_xor(tg, 1, 64);
                float x2 = __shfl_xor(tg, 2, 64);
                float x3 = __shfl_xor(tg, 3, 64);
                float tI = sel4(g,     tg, x1, x2, x3);
                float tF = sel4(g ^ 1, tg, x1, x2, x3);
                float tG = sel4(g ^ 2, tg, x1, x2, x3);
                float tO = sel4(g ^ 3, tg, x1, x2, x3);
                float cn = tF * creg0[r] + tI * tG;
                float hn = tO * tanh_fast(cn);
                if (mbk) { creg0[r] = cn; hreg0[r] = hn; }
            }
            {
                float z  = acc1[r] * (1.0f / 16384.0f) + bf2f((ushort)(xwv1 >> (16 * r)));
                float tg = tanh_fast(z);
                float x1 = __shfl_xor(tg, 1, 64);
                float x2 = __shfl_xor(tg, 2, 64);
                float x3 = __shfl_xor(tg, 3, 64);
                float tI = sel4(g,     tg, x1, x2, x3);
                float tF = sel4(g ^ 1, tg, x1, x2, x3);
                float tG = sel4(g ^ 2, tg, x1, x2, x3);
                float tO = sel4(g ^ 3, tg, x1, x2, x3);
                float cn = tF * creg1[r] + tI * tG;
                float hn = tO * tanh_fast(cn);
                if (mbk) { creg1[r] = cn; hreg1[r] = hn; }
            }
            if (notlast) {
                float a0 = hreg0[r] * 256.0f;
                float b0 = __shfl_xor(a0, 4, 64);
                float cc0 = __shfl_xor(a0, 8, 64);
                float d0 = __shfl_xor(a0, 12, 64);
                int pk0 = __builtin_amdgcn_cvt_pk_fp8_f32(a0, b0, 0, false);
                pk0     = __builtin_amdgcn_cvt_pk_fp8_f32(cc0, d0, pk0, true);
                float a1 = hreg1[r] * 256.0f;
                float b1 = __shfl_xor(a1, 4, 64);
                float cc1 = __shfl_xor(a1, 8, 64);
                float d1 = __shfl_xor(a1, 12, 64);
                int pk1 = __builtin_amdgcn_cvt_pk_fp8_f32(a1, b1, 0, false);
                pk1     = __builtin_amdgcn_cvt_pk_fp8_f32(cc1, d1, pk1, true);
                if (lr == 0) {
                    int row = m0 + lq * 4 + r;
                    __hip_atomic_store(hnxt + row * 256 + cb,     (u64)(unsigned)pk0 | tagw,
                                       __ATOMIC_RELAXED, __HIP_MEMORY_SCOPE_AGENT);
                    __hip_atomic_store(hnxt + row * 256 + cb + 1, (u64)(unsigned)pk1 | tagw,
                                       __ATOMIC_RELAXED, __HIP_MEMORY_SCOPE_AGENT);
                }
            }
        }

        if (notlast) {
            // ---- gate xw prefetch on gemm completion (pipelined: register compare) ----
            int mbn = (t + 1) >> 1;
            if (mbn >= mb_conf) {
                while (cv < 32u) {
                    __builtin_amdgcn_s_sleep(4);
                    cv = __hip_atomic_load(&cnt[mbn], __ATOMIC_RELAXED, __HIP_MEMORY_SCOPE_AGENT);
                }
                mb_conf = mbn + 1;
                int nx = mbn + 1 < 256 ? mbn + 1 : 255;
                cv = __hip_atomic_load(&cnt[nx], __ATOMIC_RELAXED, __HIP_MEMORY_SCOPE_AGENT);
                asm volatile("" ::: "memory");
            }
            // prefetch next-step inputs (overlaps with other blocks' polling)
            xwv0 = *reinterpret_cast<const u64*>(xWT + ((size_t)(t + 1) * G4_ + c0) * B_ + m0 + lq * 4);
            xwv1 = *reinterpret_cast<const u64*>(xWT + ((size_t)(t + 1) * G4_ + c1) * B_ + m0 + lq * 4);
            mask = m32[t + 1];
            const u64* tsw = hcur; hcur = hnxt; hnxt = (u64*)tsw;
        } else {
            // ---- final: write (h, h, c) fp32 ----
            if (g == 0) {
                int j0 = c0 >> 2, j1 = c1 >> 2;
                #pragma unroll
                for (int r = 0; r < 4; ++r) {
                    int row = m0 + lq * 4 + r;
                    out[row * H_ + j0]               = hreg0[r];
                    out[B_ * H_ + row * H_ + j0]     = hreg0[r];
                    out[2 * B_ * H_ + row * H_ + j0] = creg0[r];
                    out[row * H_ + j1]               = hreg1[r];
                    out[B_ * H_ + row * H_ + j1]     = hreg1[r];
                    out[2 * B_ * H_ + row * H_ + j1] = creg1[r];
                }
            }
        }
    }
}

extern "C" void kernel_launch(void* const* d_in, const int* in_sizes, int n_in,
                              void* d_out, int out_size, void* d_ws, size_t ws_size,
                              hipStream_t stream) {
    (void)in_sizes; (void)n_in; (void)out_size; (void)ws_size;
    const int*   tokens = (const int*)  d_in[0];
    const float* emb    = (const float*)d_in[1];
    const float* W      = (const float*)d_in[2];
    const float* U      = (const float*)d_in[3];
    const float* bias   = (const float*)d_in[4];

    char* ws = (char*)d_ws;
    ushort*        WT   = (ushort*)ws;                               // 4 MB
    unsigned char* UT   = (unsigned char*)(ws + (4u << 20));         // 4 MB fp8
    ushort*        xWT  = (ushort*)(ws + (8u << 20));                // 128 MB
    u64*           hA   = (u64*)(ws + (136u << 20));                 // 64 KB tagged
    u64*           hB   = hA + 8192;                                 // 64 KB tagged
    unsigned*      m32  = (unsigned*)(hB + 8192);                    // 2 KB
    unsigned*      cnt  = m32 + 512;                                 // 1 KB

    init_kernel<<<16, 256, 0, stream>>>(tokens, hA, cnt, m32);
    transpose_w_kernel<<<dim3(G4_ / 32, E_ / 32), 256, 0, stream>>>(W, WT);
    transpose_u_kernel<<<dim3(G4_ / 32, H_ / 32), 256, 0, stream>>>(U, (unsigned*)UT);
    mono_kernel<<<NSB_ + NGB_, 256, 0, stream>>>(UT, xWT, m32, hA, hB, cnt, (float*)d_out,
                                                 tokens, emb, WT, bias);
}